// Round 1
// baseline (1270.995 us; speedup 1.0000x reference)
//
#include <hip/hip_runtime.h>
#include <math.h>

#define TPB 256

__device__ __forceinline__ float lrelu(float x){ return x > 0.f ? x : 0.2f*x; }

// ---------------- CSR build (graph constant across layers) ----------------
__global__ void k_init_cnt(int* __restrict__ cnt, int N){
  int t = blockIdx.x*TPB + threadIdx.x;
  if (t < 4*N) cnt[t] = (t < 3*N) ? 1 : 0;  // GAT counts start at 1 (self-loop)
}

__global__ void k_count(const int* __restrict__ ei, int* __restrict__ cnt, int N, int E){
  int t = blockIdx.x*TPB + threadIdx.x;
  if (t >= 3*E) return;
  int r = t / E, e = t - r*E;
  int dst = ei[(r*2+1)*E + e];
  atomicAdd(&cnt[r*N + dst], 1);
  atomicAdd(&cnt[3*N + dst], 1);
}

__global__ void k_scan4(const int* __restrict__ cnt, int* __restrict__ rp, int N){
  __shared__ int sh[1024];
  __shared__ int carry;
  int a = blockIdx.x;
  const int* c = cnt + a*N;
  int* r = rp + a*(N+1);
  if (threadIdx.x == 0) carry = 0;
  __syncthreads();
  for (int base = 0; base < N; base += 1024){
    int idx = base + threadIdx.x;
    int v = (idx < N) ? c[idx] : 0;
    sh[threadIdx.x] = v;
    __syncthreads();
    for (int off = 1; off < 1024; off <<= 1){
      int t = (threadIdx.x >= off) ? sh[threadIdx.x - off] : 0;
      __syncthreads();
      sh[threadIdx.x] += t;
      __syncthreads();
    }
    if (idx < N) r[idx] = carry + sh[threadIdx.x] - v;  // exclusive
    __syncthreads();
    if (threadIdx.x == 0) carry += sh[1023];
    __syncthreads();
  }
  if (threadIdx.x == 0) r[N] = carry;
}

__global__ void k_init_cursor(const int* __restrict__ rp, int* __restrict__ cur, int N){
  int t = blockIdx.x*TPB + threadIdx.x;
  if (t >= 4*N) return;
  int a = t / N, i = t - a*N;
  cur[t] = rp[a*(N+1) + i];
}

__global__ void k_scatter(const int* __restrict__ ei, int* __restrict__ cur,
                          int* __restrict__ idx_gat, int* __restrict__ idx_hgt,
                          int N, int E){
  int t = blockIdx.x*TPB + threadIdx.x;
  int EN = E + N;
  if (t < 3*E){
    int r = t / E, e = t - r*E;
    int src = ei[(r*2)*E + e];
    int dst = ei[(r*2+1)*E + e];
    int pg = atomicAdd(&cur[r*N + dst], 1);
    idx_gat[r*EN + pg] = src;
    int ph = atomicAdd(&cur[3*N + dst], 1);
    idx_hgt[ph] = r*N + src;           // packed (rel,src)
  } else if (t < 3*E + 3*N){
    int tt = t - 3*E;
    int r = tt / N, i = tt - r*N;
    int pg = atomicAdd(&cur[r*N + i], 1);
    idx_gat[r*EN + pg] = i;            // self loop
  }
}

// ---------------- small dense GEMM: C[mat] = A @ W[mat] (+ bias) ----------------
// A:[n,K] shared; W:[nmat,K,96]; bias:[nmat,96] or null; C:[nmat,n,96]
// thread computes 8 output cols.
__global__ void k_gemm8(const float* __restrict__ A, const float* __restrict__ W,
                        const float* __restrict__ bias, float* __restrict__ C,
                        int n, int K){
  int mat = blockIdx.y;
  int t = blockIdx.x*TPB + threadIdx.x;
  if (t >= n*12) return;
  int i  = t / 12;
  int c0 = (t - i*12) * 8;
  const float* Ar = A + (size_t)i*K;
  const float* Wm = W + (size_t)mat*K*96;
  float4 a0 = make_float4(0.f,0.f,0.f,0.f), a1 = a0;
  #pragma unroll 4
  for (int k = 0; k < K; k++){
    float a = Ar[k];
    const float4* w4 = reinterpret_cast<const float4*>(Wm + (size_t)k*96 + c0);
    float4 w0 = w4[0], w1 = w4[1];
    a0.x += a*w0.x; a0.y += a*w0.y; a0.z += a*w0.z; a0.w += a*w0.w;
    a1.x += a*w1.x; a1.y += a*w1.y; a1.z += a*w1.z; a1.w += a*w1.w;
  }
  if (bias){
    const float* bp = bias + mat*96 + c0;
    a0.x += bp[0]; a0.y += bp[1]; a0.z += bp[2]; a0.w += bp[3];
    a1.x += bp[4]; a1.y += bp[5]; a1.z += bp[6]; a1.w += bp[7];
  }
  float* Cr = C + (size_t)mat*n*96 + (size_t)i*96 + c0;
  reinterpret_cast<float4*>(Cr)[0] = a0;
  reinterpret_cast<float4*>(Cr)[1] = a1;
}

// ---------------- GAT attention dots: a_src/a_dst [3,N,2] ----------------
__global__ void k_attdots(const float* __restrict__ hp, const float* __restrict__ att,
                          float* __restrict__ asrc, float* __restrict__ adst, int n){
  int t = blockIdx.x*TPB + threadIdx.x;
  if (t >= 3*n) return;
  int r = t / n;                       // t == r*n+i
  const float* row = hp + (size_t)t*96;
  const float* ap  = att + r*192;      // [2,2,48] per relation
  #pragma unroll
  for (int h = 0; h < 2; h++){
    float s = 0.f, d = 0.f;
    #pragma unroll 8
    for (int dd = 0; dd < 48; dd++){
      float v = row[h*48 + dd];
      s += v * ap[h*48 + dd];
      d += v * ap[96 + h*48 + dd];
    }
    asrc[t*2 + h] = s;
    adst[t*2 + h] = d;
  }
}

// ---------------- GAT per-relation softmax + aggregate (thread = (r,i,h)) ----------------
__global__ void k_gat_agg(const float* __restrict__ asrc, const float* __restrict__ adst,
                          const float* __restrict__ hp, const int* __restrict__ rowptr,
                          const int* __restrict__ idxg, float* __restrict__ outp,
                          int n, int Eplus){
  int t = blockIdx.x*TPB + threadIdx.x;
  if (t >= 3*n*2) return;
  int h  = t & 1;
  int ri = t >> 1;
  int i  = ri % n;
  int r  = ri / n;
  const int* rp = rowptr + r*(n+1);
  int s0 = rp[i], s1 = rp[i+1];
  const int* ix = idxg + (size_t)r*Eplus;
  const float* as = asrc + (size_t)r*n*2;
  float ad = adst[(size_t)ri*2 + h];
  float m = -1e30f;
  for (int j = s0; j < s1; j++){
    int src = ix[j];
    float lg = lrelu(as[src*2 + h] + ad);
    m = fmaxf(m, lg);
  }
  float ssum = 0.f;
  float4 num[12];
  #pragma unroll
  for (int d = 0; d < 12; d++) num[d] = make_float4(0.f,0.f,0.f,0.f);
  const float* hpb = hp + (size_t)r*n*96 + h*48;
  for (int j = s0; j < s1; j++){
    int src = ix[j];
    float lg = lrelu(as[src*2 + h] + ad);
    float e = expf(lg - m);
    ssum += e;
    const float4* hv = reinterpret_cast<const float4*>(hpb + (size_t)src*96);
    #pragma unroll
    for (int d = 0; d < 12; d++){
      float4 v = hv[d];
      num[d].x += e*v.x; num[d].y += e*v.y; num[d].z += e*v.z; num[d].w += e*v.w;
    }
  }
  float inv = 1.f / ssum;              // self-loop guarantees s1>s0
  float4* ob = reinterpret_cast<float4*>(outp + (size_t)ri*96 + h*48);
  #pragma unroll
  for (int d = 0; d < 12; d++){
    float4 v = num[d];
    v.x *= inv; v.y *= inv; v.z *= inv; v.w *= inv;
    ob[d] = v;
  }
}

// ---------------- combine 3 relations + bias, accumulate BN stats ----------------
__global__ void k_combine_stats(const float* __restrict__ gout, const float* __restrict__ b3,
                                float* __restrict__ pre, float* __restrict__ stats, int total){
  __shared__ float s1[96], s2[96];
  if (threadIdx.x < 96){ s1[threadIdx.x] = 0.f; s2[threadIdx.x] = 0.f; }
  __syncthreads();
  int nh = total;
  int idx0 = blockIdx.x*TPB*8 + threadIdx.x;
  for (int it = 0; it < 8; it++){
    int idx = idx0 + it*TPB;
    if (idx < nh){
      int c = idx % 96;
      float v = gout[idx] + gout[(size_t)nh + idx] + gout[2*(size_t)nh + idx]
              + b3[c] + b3[96 + c] + b3[192 + c];
      pre[idx] = v;
      atomicAdd(&s1[c], v);
      atomicAdd(&s2[c], v*v);
    }
  }
  __syncthreads();
  if (threadIdx.x < 96){
    atomicAdd(&stats[threadIdx.x], s1[threadIdx.x]);
    atomicAdd(&stats[96 + threadIdx.x], s2[threadIdx.x]);
  }
}

// ---------------- HGT skip-mix in place + BN stats ----------------
__global__ void k_mix_stats(float* __restrict__ pre, const float* __restrict__ h,
                            const float* __restrict__ skip, float* __restrict__ stats, int total){
  __shared__ float s1[96], s2[96];
  if (threadIdx.x < 96){ s1[threadIdx.x] = 0.f; s2[threadIdx.x] = 0.f; }
  __syncthreads();
  float sk = 1.f / (1.f + expf(-skip[0]));
  int idx0 = blockIdx.x*TPB*8 + threadIdx.x;
  for (int it = 0; it < 8; it++){
    int idx = idx0 + it*TPB;
    if (idx < total){
      int c = idx % 96;
      float v = sk*pre[idx] + (1.f - sk)*h[idx];
      pre[idx] = v;
      atomicAdd(&s1[c], v);
      atomicAdd(&s2[c], v*v);
    }
  }
  __syncthreads();
  if (threadIdx.x < 96){
    atomicAdd(&stats[threadIdx.x], s1[threadIdx.x]);
    atomicAdd(&stats[96 + threadIdx.x], s2[threadIdx.x]);
  }
}

// ---------------- BN finalize: scale/shift; re-zero sums for next BN ----------------
__global__ void k_bn_final(float* __restrict__ stats, const float* __restrict__ gamma,
                           const float* __restrict__ beta, int n){
  int c = threadIdx.x;
  if (c < 96){
    float fn = (float)n;
    float mean = stats[c] / fn;
    float var  = stats[96 + c] / fn - mean*mean;
    float iv   = rsqrtf(var + 1e-5f);
    float sc   = gamma[c] * iv;
    stats[192 + c] = sc;
    stats[288 + c] = beta[c] - mean*sc;
    stats[c] = 0.f;
    stats[96 + c] = 0.f;
  }
}

// ---------------- apply: h = lrelu(res*h + bn(pre) + inj) ----------------
__global__ void k_apply(float* __restrict__ h, const float* __restrict__ pre,
                        const float* __restrict__ stats, const float* __restrict__ inj,
                        int res, int total){
  int idx = blockIdx.x*TPB + threadIdx.x;
  if (idx >= total) return;
  int c = idx % 96;
  float v = stats[192 + c]*pre[idx] + stats[288 + c];
  if (inj) v += inj[idx];
  if (res) v += h[idx];
  h[idx] = lrelu(v);
}

// ---------------- HGT per-node K/V transforms: K_r = k·a_rel, V_r = v·m_rel ----------------
__global__ void k_kv(const float* __restrict__ kin, const float* __restrict__ vin,
                     const float* __restrict__ arel, const float* __restrict__ mrel,
                     float* __restrict__ Kb, float* __restrict__ Vb, int n){
  int t = blockIdx.x*TPB + threadIdx.x;
  if (t >= 3*n*96) return;
  int c = t % 96;
  int i = (t / 96) % n;
  int r = t / (96*n);
  int hh = c >> 4, f = c & 15;
  const float* kr = kin + (size_t)i*96 + hh*16;
  const float* vr = vin + (size_t)i*96 + hh*16;
  const float* ar = arel + (size_t)((r*6 + hh)*16)*16 + f;
  const float* mr = mrel + (size_t)((r*6 + hh)*16)*16 + f;
  float ka = 0.f, va = 0.f;
  #pragma unroll
  for (int d = 0; d < 16; d++){
    ka += kr[d] * ar[d*16];
    va += vr[d] * mr[d*16];
  }
  Kb[t] = ka;   // t == (r*n+i)*96+c
  Vb[t] = va;
}

// ---------------- HGT joint softmax + aggregate + exact GELU (thread = (i,h)) ----------------
__global__ void k_hgt_agg(const float* __restrict__ qkv, const float* __restrict__ Kb,
                          const float* __restrict__ Vb, const float* __restrict__ prel,
                          const int* __restrict__ rp4, const int* __restrict__ idxh,
                          float* __restrict__ lbuf, float* __restrict__ gbuf, int n){
  int t = blockIdx.x*TPB + threadIdx.x;
  if (t >= n*6) return;
  int h = t % 6, i = t / 6;
  float q[16];
  const float4* qp = reinterpret_cast<const float4*>(qkv + (size_t)n*96 + (size_t)i*96 + h*16);
  #pragma unroll
  for (int w = 0; w < 4; w++){
    float4 v = qp[w];
    q[4*w] = v.x; q[4*w+1] = v.y; q[4*w+2] = v.z; q[4*w+3] = v.w;
  }
  float pp0 = 0.25f*prel[h], pp1 = 0.25f*prel[6+h], pp2 = 0.25f*prel[12+h];
  const int* rp = rp4 + 3*(n+1);
  int s0 = rp[i], s1 = rp[i+1];
  float m = -1e30f;
  for (int j = s0; j < s1; j++){
    int packed = idxh[j];
    int r = packed / n;
    const float4* kp = reinterpret_cast<const float4*>(Kb + (size_t)packed*96 + h*16);
    float dot = 0.f;
    #pragma unroll
    for (int w = 0; w < 4; w++){
      float4 v = kp[w];
      dot += q[4*w]*v.x + q[4*w+1]*v.y + q[4*w+2]*v.z + q[4*w+3]*v.w;
    }
    float lg = dot * (r == 0 ? pp0 : (r == 1 ? pp1 : pp2));
    lbuf[(size_t)j*6 + h] = lg;
    m = fmaxf(m, lg);
  }
  float ssum = 0.f;
  float acc[16];
  #pragma unroll
  for (int f = 0; f < 16; f++) acc[f] = 0.f;
  for (int j = s0; j < s1; j++){
    int packed = idxh[j];
    float e = expf(lbuf[(size_t)j*6 + h] - m);
    ssum += e;
    const float4* vp = reinterpret_cast<const float4*>(Vb + (size_t)packed*96 + h*16);
    #pragma unroll
    for (int w = 0; w < 4; w++){
      float4 v = vp[w];
      acc[4*w] += e*v.x; acc[4*w+1] += e*v.y; acc[4*w+2] += e*v.z; acc[4*w+3] += e*v.w;
    }
  }
  float inv = (s1 > s0) ? 1.f/ssum : 0.f;
  float* gb = gbuf + (size_t)i*96 + h*16;
  #pragma unroll
  for (int f = 0; f < 16; f++){
    float x = acc[f]*inv;
    gb[f] = 0.5f*x*(1.f + erff(x*0.70710678118654752f));   // exact GELU
  }
}

// ---------------- final linear: out[i] = h[i]·lin_W + lin_b ----------------
__global__ void k_final_lin(const float* __restrict__ h, const float* __restrict__ w,
                            const float* __restrict__ b, float* __restrict__ out, int N){
  int i = blockIdx.x*TPB + threadIdx.x;
  if (i >= N) return;
  const float4* hr = reinterpret_cast<const float4*>(h + (size_t)i*96);
  const float4* wr = reinterpret_cast<const float4*>(w);
  float acc = 0.f;
  #pragma unroll
  for (int c = 0; c < 24; c++){
    float4 a = hr[c], q = wr[c];
    acc += a.x*q.x + a.y*q.y + a.z*q.z + a.w*q.w;
  }
  out[i] = acc + b[0];
}

// =====================================================================
extern "C" void kernel_launch(void* const* d_in, const int* in_sizes, int n_in,
                              void* d_out, int out_size, void* d_ws, size_t ws_size,
                              hipStream_t stream){
  const float* x        = (const float*)d_in[0];
  const int*   ei       = (const int*)  d_in[1];
  const float* gat0_W   = (const float*)d_in[2];
  const float* gat0_att = (const float*)d_in[3];
  const float* gat0_b   = (const float*)d_in[4];
  const float* gat_W    = (const float*)d_in[5];
  const float* gat_att  = (const float*)d_in[6];
  const float* gat_b    = (const float*)d_in[7];
  const float* bn_g     = (const float*)d_in[8];
  const float* bn_b     = (const float*)d_in[9];
  const float* kqv_W    = (const float*)d_in[10];
  const float* kqv_b    = (const float*)d_in[11];
  const float* a_rel    = (const float*)d_in[12];
  const float* m_rel    = (const float*)d_in[13];
  const float* p_rel    = (const float*)d_in[14];
  const float* hout_W   = (const float*)d_in[15];
  const float* hout_b   = (const float*)d_in[16];
  const float* skip     = (const float*)d_in[17];
  const float* proj_W   = (const float*)d_in[18];
  const float* proj_b   = (const float*)d_in[19];
  const float* lin_W    = (const float*)d_in[20];
  const float* lin_b    = (const float*)d_in[21];
  float* out = (float*)d_out;

  const int N = in_sizes[0] / 32;
  const int E = in_sizes[1] / 6;
  const size_t NH = (size_t)N * 96;
  const int nh = (int)NH;

  // ---- workspace layout (floats, then ints) ----
  float* f = (float*)d_ws;
  float* h_buf = f;  f += NH;
  float* pre   = f;  f += NH;        // also reused as lbuf during k_hgt_agg
  float* b3a   = f;  f += 3*NH;      // hp (GAT) | Kb (HGT)
  float* b3b   = f;  f += 3*NH;      // per-rel GAT out | Vb (HGT)
  float* b3c   = f;  f += 3*NH;      // qkv (HGT)
  float* aux   = f;  f += NH;        // injection | gelu(agg)
  float* asrc  = f;  f += (size_t)3*N*2;
  float* adst  = f;  f += (size_t)3*N*2;
  float* stats = f;  f += 512;
  int* ip = (int*)f;
  int* cnt     = ip;  ip += 4*N;
  int* rowptr  = ip;  ip += 4*(N+1);
  int* cursor  = ip;  ip += 4*N;
  int* idx_gat = ip;  ip += 3*(E+N);
  int* idx_hgt = ip;  ip += 3*E;
  float* lbuf = pre;                 // 3E*6 = 1.8M <= NH

  auto g1 = [](int n){ return dim3((n + TPB - 1)/TPB); };
  const dim3 gg((N*12 + TPB - 1)/TPB, 3);     // 3-matrix GEMM grid
  const dim3 g1m((N*12 + TPB - 1)/TPB, 1);    // 1-matrix GEMM grid
  const int cs_blocks = (nh + TPB*8 - 1)/(TPB*8);

  // ---- CSR build ----
  hipMemsetAsync(stats, 0, 192*sizeof(float), stream);
  k_init_cnt   <<<g1(4*N),       TPB, 0, stream>>>(cnt, N);
  k_count      <<<g1(3*E),       TPB, 0, stream>>>(ei, cnt, N, E);
  k_scan4      <<<4,            1024, 0, stream>>>(cnt, rowptr, N);
  k_init_cursor<<<g1(4*N),       TPB, 0, stream>>>(rowptr, cursor, N);
  k_scatter    <<<g1(3*E+3*N),   TPB, 0, stream>>>(ei, cursor, idx_gat, idx_hgt, N, E);

  auto run_hgt = [&](int idx, int bnidx){
    k_gemm8  <<<gg, TPB, 0, stream>>>(h_buf, kqv_W + (size_t)idx*3*96*96, kqv_b + idx*3*96, b3c, N, 96);
    k_kv     <<<g1(3*nh), TPB, 0, stream>>>(b3c, b3c + 2*NH,
                                            a_rel + (size_t)idx*3*6*256,
                                            m_rel + (size_t)idx*3*6*256, b3a, b3b, N);
    k_hgt_agg<<<g1(6*N), TPB, 0, stream>>>(b3c, b3a, b3b, p_rel + idx*18, rowptr, idx_hgt, lbuf, aux, N);
    k_gemm8  <<<g1m, TPB, 0, stream>>>(aux, hout_W + (size_t)idx*96*96, hout_b + idx*96, pre, N, 96);
    k_mix_stats<<<cs_blocks, TPB, 0, stream>>>(pre, h_buf, skip + idx, stats, nh);
    k_bn_final<<<1, 128, 0, stream>>>(stats, bn_g + bnidx*96, bn_b + bnidx*96, N);
    k_apply  <<<g1(nh), TPB, 0, stream>>>(h_buf, pre, stats, nullptr, 1, nh);
  };

  // ---- GAT layer 0 (input dim 32, no residual) ----
  k_gemm8        <<<gg, TPB, 0, stream>>>(x, gat0_W, nullptr, b3a, N, 32);
  k_attdots      <<<g1(3*N), TPB, 0, stream>>>(b3a, gat0_att, asrc, adst, N);
  k_gat_agg      <<<g1(6*N), TPB, 0, stream>>>(asrc, adst, b3a, rowptr, idx_gat, b3b, N, E+N);
  k_combine_stats<<<cs_blocks, TPB, 0, stream>>>(b3b, gat0_b, pre, stats, nh);
  k_bn_final     <<<1, 128, 0, stream>>>(stats, bn_g, bn_b, N);
  k_apply        <<<g1(nh), TPB, 0, stream>>>(h_buf, pre, stats, nullptr, 0, nh);

  // ---- GAT layers 1..3 ----
  for (int i = 0; i < 3; i++){
    int li = i + 1;
    k_gemm8        <<<gg, TPB, 0, stream>>>(h_buf, gat_W + (size_t)i*3*96*96, nullptr, b3a, N, 96);
    k_attdots      <<<g1(3*N), TPB, 0, stream>>>(b3a, gat_att + i*3*192, asrc, adst, N);
    k_gat_agg      <<<g1(6*N), TPB, 0, stream>>>(asrc, adst, b3a, rowptr, idx_gat, b3b, N, E+N);
    k_combine_stats<<<cs_blocks, TPB, 0, stream>>>(b3b, gat_b + i*3*96, pre, stats, nh);
    k_bn_final     <<<1, 128, 0, stream>>>(stats, bn_g + (1+i)*96, bn_b + (1+i)*96, N);
    const float* inj = nullptr;
    if (li == 2 || li == 3){
      k_gemm8<<<g1m, TPB, 0, stream>>>(x, proj_W + (size_t)(li-2)*32*96, proj_b + (li-2)*96, aux, N, 32);
      inj = aux;
    }
    k_apply<<<g1(nh), TPB, 0, stream>>>(h_buf, pre, stats, inj, 1, nh);
    if (li == 1) run_hgt(0, 4);
  }
  run_hgt(1, 5);

  k_final_lin<<<g1(N), TPB, 0, stream>>>(h_buf, lin_W, lin_b, out, N);
}

// Round 2
// 1109.889 us; speedup vs baseline: 1.1452x; 1.1452x over previous
//
#include <hip/hip_runtime.h>
#include <math.h>

#define TPB 256
#define GTPB 192

__device__ __forceinline__ float lrelu(float x){ return x > 0.f ? x : 0.2f*x; }

// ---------------- CSR build (graph constant across layers) ----------------
__global__ void k_init_cnt(int* __restrict__ cnt, int N){
  int t = blockIdx.x*TPB + threadIdx.x;
  if (t < 4*N) cnt[t] = (t < 3*N) ? 1 : 0;  // GAT counts start at 1 (self-loop)
}

__global__ void k_count(const int* __restrict__ ei, int* __restrict__ cnt, int N, int E){
  int t = blockIdx.x*TPB + threadIdx.x;
  if (t >= 3*E) return;
  int r = t / E, e = t - r*E;
  int dst = ei[(r*2+1)*E + e];
  atomicAdd(&cnt[r*N + dst], 1);
  atomicAdd(&cnt[3*N + dst], 1);
}

__global__ void k_scan4(const int* __restrict__ cnt, int* __restrict__ rp, int N){
  __shared__ int sh[1024];
  __shared__ int carry;
  int a = blockIdx.x;
  const int* c = cnt + a*N;
  int* r = rp + a*(N+1);
  if (threadIdx.x == 0) carry = 0;
  __syncthreads();
  for (int base = 0; base < N; base += 1024){
    int idx = base + threadIdx.x;
    int v = (idx < N) ? c[idx] : 0;
    sh[threadIdx.x] = v;
    __syncthreads();
    for (int off = 1; off < 1024; off <<= 1){
      int t = (threadIdx.x >= off) ? sh[threadIdx.x - off] : 0;
      __syncthreads();
      sh[threadIdx.x] += t;
      __syncthreads();
    }
    if (idx < N) r[idx] = carry + sh[threadIdx.x] - v;  // exclusive
    __syncthreads();
    if (threadIdx.x == 0) carry += sh[1023];
    __syncthreads();
  }
  if (threadIdx.x == 0) r[N] = carry;
}

__global__ void k_init_cursor(const int* __restrict__ rp, int* __restrict__ cur, int N){
  int t = blockIdx.x*TPB + threadIdx.x;
  if (t >= 4*N) return;
  int a = t / N, i = t - a*N;
  cur[t] = rp[a*(N+1) + i];
}

__global__ void k_scatter(const int* __restrict__ ei, int* __restrict__ cur,
                          int* __restrict__ idx_gat, int* __restrict__ idx_hgt,
                          int N, int E){
  int t = blockIdx.x*TPB + threadIdx.x;
  int EN = E + N;
  if (t < 3*E){
    int r = t / E, e = t - r*E;
    int src = ei[(r*2)*E + e];
    int dst = ei[(r*2+1)*E + e];
    int pg = atomicAdd(&cur[r*N + dst], 1);
    idx_gat[r*EN + pg] = src;
    int ph = atomicAdd(&cur[3*N + dst], 1);
    idx_hgt[ph] = r*N + src;           // packed (rel,src)
  } else if (t < 3*E + 3*N){
    int tt = t - 3*E;
    int r = tt / N, i = tt - r*N;
    int pg = atomicAdd(&cur[r*N + i], 1);
    idx_gat[r*EN + pg] = i;            // self loop
  }
}

// ---------------- LDS-tiled dense GEMM: C[mat] = A @ W[mat] (+ bias) ----------------
// A:[n,K]; W:[nmat,K,96]; C:[nmat,n,96]. Block = 192 threads -> 96 rows x 96 cols tile.
// Thread computes 6 rows x 8 cols. W staged in LDS (<=36KB).
__global__ __launch_bounds__(GTPB) void k_gemm_t(const float* __restrict__ A,
                        const float* __restrict__ W,
                        const float* __restrict__ bias, float* __restrict__ C,
                        int n, int K){
  __shared__ float Wl[96*96];
  int mat = blockIdx.y;
  const float4* Wm4 = reinterpret_cast<const float4*>(W + (size_t)mat*K*96);
  for (int idx = threadIdx.x; idx < K*24; idx += GTPB)
    reinterpret_cast<float4*>(Wl)[idx] = Wm4[idx];
  __syncthreads();

  int cg = threadIdx.x % 12;
  int rg = threadIdx.x / 12;     // 0..15
  int c0 = cg*8;
  int r0 = blockIdx.x*96 + rg*6;

  float acc[6][8];
  #pragma unroll
  for (int u = 0; u < 6; u++)
    #pragma unroll
    for (int c = 0; c < 8; c++) acc[u][c] = 0.f;

  for (int k = 0; k < K; k += 4){
    float4 a[6];
    #pragma unroll
    for (int u = 0; u < 6; u++){
      int r = r0 + u;
      a[u] = (r < n) ? *reinterpret_cast<const float4*>(A + (size_t)r*K + k)
                     : make_float4(0.f,0.f,0.f,0.f);
    }
    #pragma unroll
    for (int kk = 0; kk < 4; kk++){
      float4 w0 = *reinterpret_cast<const float4*>(Wl + (k+kk)*96 + c0);
      float4 w1 = *reinterpret_cast<const float4*>(Wl + (k+kk)*96 + c0 + 4);
      float wv0 = w0.x, wv1 = w0.y, wv2 = w0.z, wv3 = w0.w;
      float wv4 = w1.x, wv5 = w1.y, wv6 = w1.z, wv7 = w1.w;
      #pragma unroll
      for (int u = 0; u < 6; u++){
        float av = (kk==0) ? a[u].x : (kk==1) ? a[u].y : (kk==2) ? a[u].z : a[u].w;
        acc[u][0] += av*wv0; acc[u][1] += av*wv1; acc[u][2] += av*wv2; acc[u][3] += av*wv3;
        acc[u][4] += av*wv4; acc[u][5] += av*wv5; acc[u][6] += av*wv6; acc[u][7] += av*wv7;
      }
    }
  }

  float b[8];
  if (bias){
    const float* bp = bias + mat*96 + c0;
    #pragma unroll
    for (int c = 0; c < 8; c++) b[c] = bp[c];
  } else {
    #pragma unroll
    for (int c = 0; c < 8; c++) b[c] = 0.f;
  }
  #pragma unroll
  for (int u = 0; u < 6; u++){
    int r = r0 + u;
    if (r < n){
      float* Cr = C + (size_t)mat*n*96 + (size_t)r*96 + c0;
      float4 o0 = make_float4(acc[u][0]+b[0], acc[u][1]+b[1], acc[u][2]+b[2], acc[u][3]+b[3]);
      float4 o1 = make_float4(acc[u][4]+b[4], acc[u][5]+b[5], acc[u][6]+b[6], acc[u][7]+b[7]);
      reinterpret_cast<float4*>(Cr)[0] = o0;
      reinterpret_cast<float4*>(Cr)[1] = o1;
    }
  }
}

// ---------------- GAT attention dots: a_src/a_dst [3,N,2] ----------------
__global__ void k_attdots(const float* __restrict__ hp, const float* __restrict__ att,
                          float* __restrict__ asrc, float* __restrict__ adst, int n){
  int t = blockIdx.x*TPB + threadIdx.x;
  if (t >= 3*n) return;
  int r = t / n;                       // t == r*n+i
  const float* row = hp + (size_t)t*96;
  const float* ap  = att + r*192;      // [2,2,48] per relation
  #pragma unroll
  for (int h = 0; h < 2; h++){
    float s = 0.f, d = 0.f;
    #pragma unroll 8
    for (int dd = 0; dd < 48; dd++){
      float v = row[h*48 + dd];
      s += v * ap[h*48 + dd];
      d += v * ap[96 + h*48 + dd];
    }
    asrc[t*2 + h] = s;
    adst[t*2 + h] = d;
  }
}

// ---------------- GAT per-relation softmax + aggregate (thread = (r,i,h)) ----------------
__global__ void k_gat_agg(const float* __restrict__ asrc, const float* __restrict__ adst,
                          const float* __restrict__ hp, const int* __restrict__ rowptr,
                          const int* __restrict__ idxg, float* __restrict__ outp,
                          int n, int Eplus){
  int t = blockIdx.x*TPB + threadIdx.x;
  if (t >= 3*n*2) return;
  int h  = t & 1;
  int ri = t >> 1;
  int i  = ri % n;
  int r  = ri / n;
  const int* rp = rowptr + r*(n+1);
  int s0 = rp[i], s1 = rp[i+1];
  const int* ix = idxg + (size_t)r*Eplus;
  const float* as = asrc + (size_t)r*n*2;
  float ad = adst[(size_t)ri*2 + h];
  float m = -1e30f;
  for (int j = s0; j < s1; j++){
    int src = ix[j];
    float lg = lrelu(as[src*2 + h] + ad);
    m = fmaxf(m, lg);
  }
  float ssum = 0.f;
  float4 num[12];
  #pragma unroll
  for (int d = 0; d < 12; d++) num[d] = make_float4(0.f,0.f,0.f,0.f);
  const float* hpb = hp + (size_t)r*n*96 + h*48;
  for (int j = s0; j < s1; j++){
    int src = ix[j];
    float lg = lrelu(as[src*2 + h] + ad);
    float e = expf(lg - m);
    ssum += e;
    const float4* hv = reinterpret_cast<const float4*>(hpb + (size_t)src*96);
    #pragma unroll
    for (int d = 0; d < 12; d++){
      float4 v = hv[d];
      num[d].x += e*v.x; num[d].y += e*v.y; num[d].z += e*v.z; num[d].w += e*v.w;
    }
  }
  float inv = 1.f / ssum;              // self-loop guarantees s1>s0
  float4* ob = reinterpret_cast<float4*>(outp + (size_t)ri*96 + h*48);
  #pragma unroll
  for (int d = 0; d < 12; d++){
    float4 v = num[d];
    v.x *= inv; v.y *= inv; v.z *= inv; v.w *= inv;
    ob[d] = v;
  }
}

// ---------------- combine 3 relations + bias, accumulate BN stats ----------------
__global__ void k_combine_stats(const float* __restrict__ gout, const float* __restrict__ b3,
                                float* __restrict__ pre, float* __restrict__ stats, int total){
  __shared__ float s1[96], s2[96];
  if (threadIdx.x < 96){ s1[threadIdx.x] = 0.f; s2[threadIdx.x] = 0.f; }
  __syncthreads();
  int nh = total;
  int idx0 = blockIdx.x*TPB*8 + threadIdx.x;
  for (int it = 0; it < 8; it++){
    int idx = idx0 + it*TPB;
    if (idx < nh){
      int c = idx % 96;
      float v = gout[idx] + gout[(size_t)nh + idx] + gout[2*(size_t)nh + idx]
              + b3[c] + b3[96 + c] + b3[192 + c];
      pre[idx] = v;
      atomicAdd(&s1[c], v);
      atomicAdd(&s2[c], v*v);
    }
  }
  __syncthreads();
  if (threadIdx.x < 96){
    atomicAdd(&stats[threadIdx.x], s1[threadIdx.x]);
    atomicAdd(&stats[96 + threadIdx.x], s2[threadIdx.x]);
  }
}

// ---------------- HGT skip-mix in place + BN stats ----------------
__global__ void k_mix_stats(float* __restrict__ pre, const float* __restrict__ h,
                            const float* __restrict__ skip, float* __restrict__ stats, int total){
  __shared__ float s1[96], s2[96];
  if (threadIdx.x < 96){ s1[threadIdx.x] = 0.f; s2[threadIdx.x] = 0.f; }
  __syncthreads();
  float sk = 1.f / (1.f + expf(-skip[0]));
  int idx0 = blockIdx.x*TPB*8 + threadIdx.x;
  for (int it = 0; it < 8; it++){
    int idx = idx0 + it*TPB;
    if (idx < total){
      int c = idx % 96;
      float v = sk*pre[idx] + (1.f - sk)*h[idx];
      pre[idx] = v;
      atomicAdd(&s1[c], v);
      atomicAdd(&s2[c], v*v);
    }
  }
  __syncthreads();
  if (threadIdx.x < 96){
    atomicAdd(&stats[threadIdx.x], s1[threadIdx.x]);
    atomicAdd(&stats[96 + threadIdx.x], s2[threadIdx.x]);
  }
}

// ---------------- BN finalize: scale/shift; re-zero sums for next BN ----------------
__global__ void k_bn_final(float* __restrict__ stats, const float* __restrict__ gamma,
                           const float* __restrict__ beta, int n){
  int c = threadIdx.x;
  if (c < 96){
    float fn = (float)n;
    float mean = stats[c] / fn;
    float var  = stats[96 + c] / fn - mean*mean;
    float iv   = rsqrtf(var + 1e-5f);
    float sc   = gamma[c] * iv;
    stats[192 + c] = sc;
    stats[288 + c] = beta[c] - mean*sc;
    stats[c] = 0.f;
    stats[96 + c] = 0.f;
  }
}

// ---------------- apply: h = lrelu(res*h + bn(pre) + inj) ----------------
__global__ void k_apply(float* __restrict__ h, const float* __restrict__ pre,
                        const float* __restrict__ stats, const float* __restrict__ inj,
                        int res, int total){
  int idx = blockIdx.x*TPB + threadIdx.x;
  if (idx >= total) return;
  int c = idx % 96;
  float v = stats[192 + c]*pre[idx] + stats[288 + c];
  if (inj) v += inj[idx];
  if (res) v += h[idx];
  h[idx] = lrelu(v);
}

// ---------------- HGT per-node K/V transforms: K_r = k·a_rel, V_r = v·m_rel ----------------
__global__ void k_kv(const float* __restrict__ kin, const float* __restrict__ vin,
                     const float* __restrict__ arel, const float* __restrict__ mrel,
                     float* __restrict__ Kb, float* __restrict__ Vb, int n){
  int t = blockIdx.x*TPB + threadIdx.x;
  if (t >= 3*n*96) return;
  int c = t % 96;
  int i = (t / 96) % n;
  int r = t / (96*n);
  int hh = c >> 4, f = c & 15;
  const float* kr = kin + (size_t)i*96 + hh*16;
  const float* vr = vin + (size_t)i*96 + hh*16;
  const float* ar = arel + (size_t)((r*6 + hh)*16)*16 + f;
  const float* mr = mrel + (size_t)((r*6 + hh)*16)*16 + f;
  float ka = 0.f, va = 0.f;
  #pragma unroll
  for (int d = 0; d < 16; d++){
    ka += kr[d] * ar[d*16];
    va += vr[d] * mr[d*16];
  }
  Kb[t] = ka;   // t == (r*n+i)*96+c
  Vb[t] = va;
}

// ---------------- HGT joint softmax + aggregate + exact GELU (thread = (i,h)) ----------------
__global__ void k_hgt_agg(const float* __restrict__ qkv, const float* __restrict__ Kb,
                          const float* __restrict__ Vb, const float* __restrict__ prel,
                          const int* __restrict__ rp4, const int* __restrict__ idxh,
                          float* __restrict__ lbuf, float* __restrict__ gbuf, int n){
  int t = blockIdx.x*TPB + threadIdx.x;
  if (t >= n*6) return;
  int h = t % 6, i = t / 6;
  float q[16];
  const float4* qp = reinterpret_cast<const float4*>(qkv + (size_t)n*96 + (size_t)i*96 + h*16);
  #pragma unroll
  for (int w = 0; w < 4; w++){
    float4 v = qp[w];
    q[4*w] = v.x; q[4*w+1] = v.y; q[4*w+2] = v.z; q[4*w+3] = v.w;
  }
  float pp0 = 0.25f*prel[h], pp1 = 0.25f*prel[6+h], pp2 = 0.25f*prel[12+h];
  const int* rp = rp4 + 3*(n+1);
  int s0 = rp[i], s1 = rp[i+1];
  float m = -1e30f;
  for (int j = s0; j < s1; j++){
    int packed = idxh[j];
    int r = packed / n;
    const float4* kp = reinterpret_cast<const float4*>(Kb + (size_t)packed*96 + h*16);
    float dot = 0.f;
    #pragma unroll
    for (int w = 0; w < 4; w++){
      float4 v = kp[w];
      dot += q[4*w]*v.x + q[4*w+1]*v.y + q[4*w+2]*v.z + q[4*w+3]*v.w;
    }
    float lg = dot * (r == 0 ? pp0 : (r == 1 ? pp1 : pp2));
    lbuf[(size_t)j*6 + h] = lg;
    m = fmaxf(m, lg);
  }
  float ssum = 0.f;
  float acc[16];
  #pragma unroll
  for (int f = 0; f < 16; f++) acc[f] = 0.f;
  for (int j = s0; j < s1; j++){
    int packed = idxh[j];
    float e = expf(lbuf[(size_t)j*6 + h] - m);
    ssum += e;
    const float4* vp = reinterpret_cast<const float4*>(Vb + (size_t)packed*96 + h*16);
    #pragma unroll
    for (int w = 0; w < 4; w++){
      float4 v = vp[w];
      acc[4*w] += e*v.x; acc[4*w+1] += e*v.y; acc[4*w+2] += e*v.z; acc[4*w+3] += e*v.w;
    }
  }
  float inv = (s1 > s0) ? 1.f/ssum : 0.f;
  float* gb = gbuf + (size_t)i*96 + h*16;
  #pragma unroll
  for (int f = 0; f < 16; f++){
    float x = acc[f]*inv;
    gb[f] = 0.5f*x*(1.f + erff(x*0.70710678118654752f));   // exact GELU
  }
}

// ---------------- final linear: out[i] = h[i]·lin_W + lin_b ----------------
__global__ void k_final_lin(const float* __restrict__ h, const float* __restrict__ w,
                            const float* __restrict__ b, float* __restrict__ out, int N){
  int i = blockIdx.x*TPB + threadIdx.x;
  if (i >= N) return;
  const float4* hr = reinterpret_cast<const float4*>(h + (size_t)i*96);
  const float4* wr = reinterpret_cast<const float4*>(w);
  float acc = 0.f;
  #pragma unroll
  for (int c = 0; c < 24; c++){
    float4 a = hr[c], q = wr[c];
    acc += a.x*q.x + a.y*q.y + a.z*q.z + a.w*q.w;
  }
  out[i] = acc + b[0];
}

// =====================================================================
extern "C" void kernel_launch(void* const* d_in, const int* in_sizes, int n_in,
                              void* d_out, int out_size, void* d_ws, size_t ws_size,
                              hipStream_t stream){
  const float* x        = (const float*)d_in[0];
  const int*   ei       = (const int*)  d_in[1];
  const float* gat0_W   = (const float*)d_in[2];
  const float* gat0_att = (const float*)d_in[3];
  const float* gat0_b   = (const float*)d_in[4];
  const float* gat_W    = (const float*)d_in[5];
  const float* gat_att  = (const float*)d_in[6];
  const float* gat_b    = (const float*)d_in[7];
  const float* bn_g     = (const float*)d_in[8];
  const float* bn_b     = (const float*)d_in[9];
  const float* kqv_W    = (const float*)d_in[10];
  const float* kqv_b    = (const float*)d_in[11];
  const float* a_rel    = (const float*)d_in[12];
  const float* m_rel    = (const float*)d_in[13];
  const float* p_rel    = (const float*)d_in[14];
  const float* hout_W   = (const float*)d_in[15];
  const float* hout_b   = (const float*)d_in[16];
  const float* skip     = (const float*)d_in[17];
  const float* proj_W   = (const float*)d_in[18];
  const float* proj_b   = (const float*)d_in[19];
  const float* lin_W    = (const float*)d_in[20];
  const float* lin_b    = (const float*)d_in[21];
  float* out = (float*)d_out;

  const int N = in_sizes[0] / 32;
  const int E = in_sizes[1] / 6;
  const size_t NH = (size_t)N * 96;
  const int nh = (int)NH;

  // ---- workspace layout (floats, then ints) ----
  float* f = (float*)d_ws;
  float* h_buf = f;  f += NH;
  float* pre   = f;  f += NH;        // also reused as lbuf during k_hgt_agg
  float* b3a   = f;  f += 3*NH;      // hp (GAT) | Kb (HGT)
  float* b3b   = f;  f += 3*NH;      // per-rel GAT out | Vb (HGT)
  float* b3c   = f;  f += 3*NH;      // qkv (HGT)
  float* aux   = f;  f += NH;        // injection | gelu(agg)
  float* asrc  = f;  f += (size_t)3*N*2;
  float* adst  = f;  f += (size_t)3*N*2;
  float* stats = f;  f += 512;
  int* ip = (int*)f;
  int* cnt     = ip;  ip += 4*N;
  int* rowptr  = ip;  ip += 4*(N+1);
  int* cursor  = ip;  ip += 4*N;
  int* idx_gat = ip;  ip += 3*(E+N);
  int* idx_hgt = ip;  ip += 3*E;
  float* lbuf = pre;                 // 3E*6 = 1.8M <= NH

  auto g1 = [](int n){ return dim3((n + TPB - 1)/TPB); };
  const int gx = (N + 95)/96;                 // GEMM row-tiles
  const dim3 gg(gx, 3);                       // 3-matrix GEMM grid
  const dim3 g1m(gx, 1);                      // 1-matrix GEMM grid
  const int cs_blocks = (nh + TPB*8 - 1)/(TPB*8);

  // ---- CSR build ----
  hipMemsetAsync(stats, 0, 192*sizeof(float), stream);
  k_init_cnt   <<<g1(4*N),       TPB, 0, stream>>>(cnt, N);
  k_count      <<<g1(3*E),       TPB, 0, stream>>>(ei, cnt, N, E);
  k_scan4      <<<4,            1024, 0, stream>>>(cnt, rowptr, N);
  k_init_cursor<<<g1(4*N),       TPB, 0, stream>>>(rowptr, cursor, N);
  k_scatter    <<<g1(3*E+3*N),   TPB, 0, stream>>>(ei, cursor, idx_gat, idx_hgt, N, E);

  auto run_hgt = [&](int idx, int bnidx){
    k_gemm_t <<<gg, GTPB, 0, stream>>>(h_buf, kqv_W + (size_t)idx*3*96*96, kqv_b + idx*3*96, b3c, N, 96);
    k_kv     <<<g1(3*nh), TPB, 0, stream>>>(b3c, b3c + 2*NH,
                                            a_rel + (size_t)idx*3*6*256,
                                            m_rel + (size_t)idx*3*6*256, b3a, b3b, N);
    k_hgt_agg<<<g1(6*N), TPB, 0, stream>>>(b3c, b3a, b3b, p_rel + idx*18, rowptr, idx_hgt, lbuf, aux, N);
    k_gemm_t <<<g1m, GTPB, 0, stream>>>(aux, hout_W + (size_t)idx*96*96, hout_b + idx*96, pre, N, 96);
    k_mix_stats<<<cs_blocks, TPB, 0, stream>>>(pre, h_buf, skip + idx, stats, nh);
    k_bn_final<<<1, 128, 0, stream>>>(stats, bn_g + bnidx*96, bn_b + bnidx*96, N);
    k_apply  <<<g1(nh), TPB, 0, stream>>>(h_buf, pre, stats, nullptr, 1, nh);
  };

  // ---- GAT layer 0 (input dim 32, no residual) ----
  k_gemm_t       <<<gg, GTPB, 0, stream>>>(x, gat0_W, nullptr, b3a, N, 32);
  k_attdots      <<<g1(3*N), TPB, 0, stream>>>(b3a, gat0_att, asrc, adst, N);
  k_gat_agg      <<<g1(6*N), TPB, 0, stream>>>(asrc, adst, b3a, rowptr, idx_gat, b3b, N, E+N);
  k_combine_stats<<<cs_blocks, TPB, 0, stream>>>(b3b, gat0_b, pre, stats, nh);
  k_bn_final     <<<1, 128, 0, stream>>>(stats, bn_g, bn_b, N);
  k_apply        <<<g1(nh), TPB, 0, stream>>>(h_buf, pre, stats, nullptr, 0, nh);

  // ---- GAT layers 1..3 ----
  for (int i = 0; i < 3; i++){
    int li = i + 1;
    k_gemm_t       <<<gg, GTPB, 0, stream>>>(h_buf, gat_W + (size_t)i*3*96*96, nullptr, b3a, N, 96);
    k_attdots      <<<g1(3*N), TPB, 0, stream>>>(b3a, gat_att + i*3*192, asrc, adst, N);
    k_gat_agg      <<<g1(6*N), TPB, 0, stream>>>(asrc, adst, b3a, rowptr, idx_gat, b3b, N, E+N);
    k_combine_stats<<<cs_blocks, TPB, 0, stream>>>(b3b, gat_b + i*3*96, pre, stats, nh);
    k_bn_final     <<<1, 128, 0, stream>>>(stats, bn_g + (1+i)*96, bn_b + (1+i)*96, N);
    const float* inj = nullptr;
    if (li == 2 || li == 3){
      k_gemm_t<<<g1m, GTPB, 0, stream>>>(x, proj_W + (size_t)(li-2)*32*96, proj_b + (li-2)*96, aux, N, 32);
      inj = aux;
    }
    k_apply<<<g1(nh), TPB, 0, stream>>>(h_buf, pre, stats, inj, 1, nh);
    if (li == 1) run_hgt(0, 4);
  }
  run_hgt(1, 5);

  k_final_lin<<<g1(N), TPB, 0, stream>>>(h_buf, lin_W, lin_b, out, N);
}